// Round 12
// baseline (236.084 us; speedup 1.0000x reference)
//
#include <hip/hip_runtime.h>
#include <math.h>

// out[M,N] = round-clip(x*(127/max(x))) int8  @  weight_q[N,K]^T int8
//            -> i32 acc -> * (max(x)/127) * qscales[n] + bias[n]
#define MDIM 8192
#define KDIM 4096
#define NDIM 4096

typedef int v4i __attribute__((ext_vector_type(4)));
typedef int v16i __attribute__((ext_vector_type(16)));

__device__ __forceinline__ void gload_lds16(const void* g, void* l) {
  __builtin_amdgcn_global_load_lds(
      (const __attribute__((address_space(1))) void*)g,
      (__attribute__((address_space(3))) void*)l,
      16, 0, 0);
}

// ---------------- kernel 1: global max(x) -> monotonic uint key ----------------
__global__ void __launch_bounds__(256) kmax(const float* __restrict__ x,
                                            unsigned int* __restrict__ key_out) {
  const int n4 = MDIM * KDIM / 4;
  int tid = blockIdx.x * blockDim.x + threadIdx.x;
  int stride = gridDim.x * blockDim.x;
  float m = -3.4e38f;
  const float4* x4 = (const float4*)x;
  for (int i = tid; i < n4; i += stride) {
    float4 v = x4[i];
    m = fmaxf(m, fmaxf(fmaxf(v.x, v.y), fmaxf(v.z, v.w)));
  }
  #pragma unroll
  for (int off = 32; off > 0; off >>= 1)
    m = fmaxf(m, __shfl_down(m, off, 64));
  __shared__ float sm[4];
  int lane = threadIdx.x & 63, wv = threadIdx.x >> 6;
  if (lane == 0) sm[wv] = m;
  __syncthreads();
  if (threadIdx.x == 0) {
    m = fmaxf(fmaxf(sm[0], sm[1]), fmaxf(sm[2], sm[3]));
    unsigned b = __float_as_uint(m);
    unsigned key = (b & 0x80000000u) ? ~b : (b | 0x80000000u);  // order-preserving
    atomicMax(key_out, key);
  }
}

__device__ __forceinline__ float key_to_float(unsigned key) {
  unsigned b = (key & 0x80000000u) ? (key & 0x7FFFFFFFu) : ~key;
  return __uint_as_float(b);
}

// -------- kernel 1b: repack weights -> contiguous int8 (detection fused) -------
__global__ void __launch_bounds__(256) kpackw(const int* __restrict__ w,
                                              signed char* __restrict__ w8) {
  __shared__ int smode;
  int ok = 1;
  #pragma unroll
  for (int i = 0; i < 16; ++i) {
    int v = w[threadIdx.x * 16 + i];
    ok &= (v >= -128) & (v <= 127);
  }
  if (threadIdx.x == 0) smode = 1;
  __syncthreads();
  if (!ok) atomicAnd(&smode, 0);
  __syncthreads();
  const int mode = smode;

  const int n16 = NDIM * KDIM / 16;
  int tid = blockIdx.x * blockDim.x + threadIdx.x;
  int stride = gridDim.x * blockDim.x;
  int4* dst = (int4*)w8;
  if (mode) {
    const int4* src = (const int4*)w;
    for (int i = tid; i < n16; i += stride) {
      int4 r;
      #pragma unroll
      for (int q = 0; q < 4; ++q) {
        int4 a = src[(size_t)i * 4 + q];
        int packed = (a.x & 255) | ((a.y & 255) << 8) |
                     ((a.z & 255) << 16) | ((a.w & 255) << 24);
        ((int*)&r)[q] = packed;
      }
      dst[i] = r;
    }
  } else {
    const int4* src = (const int4*)w;
    for (int i = tid; i < n16; i += stride) dst[i] = src[i];
  }
}

// ---------------- kernel 2: quantize x -> int8 ----------------
__device__ __forceinline__ int pack4(float4 v, float s) {
  int q0 = (int)fminf(fmaxf(rintf(v.x * s), -128.f), 127.f);
  int q1 = (int)fminf(fmaxf(rintf(v.y * s), -128.f), 127.f);
  int q2 = (int)fminf(fmaxf(rintf(v.z * s), -128.f), 127.f);
  int q3 = (int)fminf(fmaxf(rintf(v.w * s), -128.f), 127.f);
  return (q0 & 255) | ((q1 & 255) << 8) | ((q2 & 255) << 16) | ((q3 & 255) << 24);
}

__global__ void __launch_bounds__(256) kquant(const float* __restrict__ x,
                                              signed char* __restrict__ x8,
                                              const unsigned* __restrict__ keyp) {
  float s = 127.0f / key_to_float(*keyp);
  const int n16 = MDIM * KDIM / 16;
  int tid = blockIdx.x * blockDim.x + threadIdx.x;
  int stride = gridDim.x * blockDim.x;
  const float4* x4 = (const float4*)x;
  int4* out16 = (int4*)x8;
  for (int i = tid; i < n16; i += stride) {
    const float4* src = x4 + (size_t)i * 4;
    int4 r;
    r.x = pack4(src[0], s);
    r.y = pack4(src[1], s);
    r.z = pack4(src[2], s);
    r.w = pack4(src[3], s);
    out16[i] = r;
  }
}

// ------ kernel 3: int8 256x256 GEMM, mfma_i32_32x32x32_i8, R9 schedule ---------
// BM=BN=256, BK=128 int8. 8 waves (2M x 4N), wave tile 128x64 = 4x2 frags 32x32,
// 4 K-steps of 32 -> 32 MFMA/wave/tile (half of the 16x16 form, +12% ceiling).
// LDS image and staging identical to R9 (verified): [par][A/B][half] 8 x 16 KiB.
// Fragment maps: A/B row=lane&31, k=(lane>>5)*16+j; C/D col=lane&31,
// row=(reg&3)+8*(reg>>2)+4*(lane>>5). XOR slot swizzle spreads a 32-row b128
// read to exactly 8 words/bank (the b128 floor -- balanced).
constexpr int BM = 256, BN = 256, BK = 128;
constexpr int NT = KDIM / BK;  // 32 (even: wrapped-tail parity matches)

__device__ __forceinline__ v16i mfma32(v4i a, v4i b, v16i c) {
  return __builtin_amdgcn_mfma_i32_32x32x32_i8(a, b, c, 0, 0, 0);
}

// End-of-phase barrier (no memory-queue wait).
#define PHASE_BAR()                                         \
  do {                                                      \
    __builtin_amdgcn_s_barrier();                           \
    __builtin_amdgcn_sched_barrier(0);                      \
  } while (0)

// K-tile boundary: single counted wait (3 phases of loads stay in flight).
#define TILE_END()                                          \
  do {                                                      \
    asm volatile("s_waitcnt vmcnt(6)" ::: "memory");        \
    __builtin_amdgcn_s_barrier();                           \
    __builtin_amdgcn_sched_barrier(0);                      \
  } while (0)

__global__ void __launch_bounds__(512, 2) kgemm(
    const signed char* __restrict__ A8,   // [M][K]
    const signed char* __restrict__ W8,   // [N][K]
    const float* __restrict__ qs,
    const float* __restrict__ bias,
    const unsigned* __restrict__ keyp,
    float* __restrict__ out) {            // [M][N]
  __shared__ alignas(1024) signed char lds[2][2][2][128 * 128];  // [par][A/B][half]

  const int nbn = NDIM / BN;                  // 16
  const int nwg = (MDIM / BM) * nbn;          // 512 (divisible by 8)
  int bid = blockIdx.x;
  int wg = (bid & 7) * (nwg / 8) + (bid >> 3);  // XCD-contiguous
  const int brow = (wg / nbn) * BM;
  const int bcol = (wg % nbn) * BN;

  const int tid = threadIdx.x;
  const int lane = tid & 63;
  const int wv = tid >> 6;                    // 0..7
  const int wr = wv >> 2, wc = wv & 3;        // 2 x 4 wave grid
  const int l31 = lane & 31, hi2 = lane >> 5, l7 = lane & 7;

  const signed char* Abase = A8 + (size_t)brow * KDIM;
  const signed char* Bbase = W8 + (size_t)bcol * KDIM;

  // Stage A-half h of K-tile t (identical to R9; wrapped tail -> dead slots).
  auto stageA = [&](int t, int h) {
    signed char* dst = &lds[t & 1][0][h][0];
    const size_t k0 = (size_t)(t & (NT - 1)) * BK;
    #pragma unroll
    for (int l = 0; l < 2; ++l) {
      int p = l * 512 + tid;
      int r = p >> 3, s = p & 7;
      int R = ((r >> 6) << 7) + h * 64 + (r & 63);
      int g = s ^ (r & 7);
      gload_lds16(Abase + (size_t)R * KDIM + k0 + g * 16, dst + p * 16);
    }
  };
  auto stageB = [&](int t, int h) {
    signed char* dst = &lds[t & 1][1][h][0];
    const size_t k0 = (size_t)(t & (NT - 1)) * BK;
    #pragma unroll
    for (int l = 0; l < 2; ++l) {
      int p = l * 512 + tid;
      int r = p >> 3, s = p & 7;
      int R = ((r >> 5) << 6) + h * 32 + (r & 31);
      int g = s ^ (r & 7);
      gload_lds16(Bbase + (size_t)R * KDIM + k0 + g * 16, dst + p * 16);
    }
  };
  // 32x32 fragment reads. A: m-block mb (0..3) -> half mb>>1, local row
  // wr*64 + (mb&1)*32 + l31. B: n-block nb (0..1) -> half nb, local row
  // wc*32 + l31. k-chunk = ks*2 + hi2, slot = chunk ^ (local_row & 7) = ^ l7.
  auto readA = [&](int par, int mb, int ks) -> v4i {
    int r = wr * 64 + (mb & 1) * 32 + l31;
    int s = (ks * 2 + hi2) ^ l7;
    return *(const v4i*)&lds[par][0][mb >> 1][r * 128 + s * 16];
  };
  auto readB = [&](int par, int nb, int ks) -> v4i {
    int r = wc * 32 + l31;
    int s = (ks * 2 + hi2) ^ l7;
    return *(const v4i*)&lds[par][1][nb][r * 128 + s * 16];
  };

  v16i acc[4][2];
  #pragma unroll
  for (int i = 0; i < 4; ++i)
    #pragma unroll
    for (int j = 0; j < 2; ++j)
      #pragma unroll
      for (int e = 0; e < 16; ++e) acc[i][j][e] = 0;

  // Prologue: 7 halves in consumption order; vmcnt(6) forces all 4 tile-0
  // halves landed.
  stageA(0, 0); stageB(0, 0); stageB(0, 1); stageA(0, 1);
  stageA(1, 0); stageB(1, 0); stageB(1, 1);
  asm volatile("s_waitcnt vmcnt(6)" ::: "memory");
  __builtin_amdgcn_s_barrier();
  __builtin_amdgcn_sched_barrier(0);

  #pragma unroll 2
  for (int t = 0; t < NT; ++t) {
    const int par = t & 1;
    v4i afr01[2][4], afr23[2][4], bfr0[4], bfr1[4];

    // ---- phase 0: read A mb0-1 (8) + B nb0 (4), stage A(t+1,1),
    //      MFMA mb0-1 x nb0 ----
    #pragma unroll
    for (int mb = 0; mb < 2; ++mb)
      #pragma unroll
      for (int ks = 0; ks < 4; ++ks) afr01[mb][ks] = readA(par, mb, ks);
    #pragma unroll
    for (int ks = 0; ks < 4; ++ks) bfr0[ks] = readB(par, 0, ks);
    stageA(t + 1, 1);
    __builtin_amdgcn_sched_barrier(0);
    __builtin_amdgcn_s_setprio(1);
    #pragma unroll
    for (int mb = 0; mb < 2; ++mb)
      #pragma unroll
      for (int ks = 0; ks < 4; ++ks)
        acc[mb][0] = mfma32(afr01[mb][ks], bfr0[ks], acc[mb][0]);
    __builtin_amdgcn_s_setprio(0);
    PHASE_BAR();

    // ---- phase 1: read B nb1 (4), stage A(t+2,0), MFMA mb0-1 x nb1 ----
    #pragma unroll
    for (int ks = 0; ks < 4; ++ks) bfr1[ks] = readB(par, 1, ks);
    stageA(t + 2, 0);
    __builtin_amdgcn_sched_barrier(0);
    __builtin_amdgcn_s_setprio(1);
    #pragma unroll
    for (int mb = 0; mb < 2; ++mb)
      #pragma unroll
      for (int ks = 0; ks < 4; ++ks)
        acc[mb][1] = mfma32(afr01[mb][ks], bfr1[ks], acc[mb][1]);
    __builtin_amdgcn_s_setprio(0);
    PHASE_BAR();

    // ---- phase 2: read A mb2-3 (8), stage B(t+2,0), MFMA mb2-3 x nb0 ----
    #pragma unroll
    for (int mb = 0; mb < 2; ++mb)
      #pragma unroll
      for (int ks = 0; ks < 4; ++ks) afr23[mb][ks] = readA(par, 2 + mb, ks);
    stageB(t + 2, 0);
    __builtin_amdgcn_sched_barrier(0);
    __builtin_amdgcn_s_setprio(1);
    #pragma unroll
    for (int mb = 0; mb < 2; ++mb)
      #pragma unroll
      for (int ks = 0; ks < 4; ++ks)
        acc[2 + mb][0] = mfma32(afr23[mb][ks], bfr0[ks], acc[2 + mb][0]);
    __builtin_amdgcn_s_setprio(0);
    PHASE_BAR();

    // ---- phase 3: stage B(t+2,1), MFMA mb2-3 x nb1, counted tile wait ----
    stageB(t + 2, 1);
    __builtin_amdgcn_sched_barrier(0);
    __builtin_amdgcn_s_setprio(1);
    #pragma unroll
    for (int mb = 0; mb < 2; ++mb)
      #pragma unroll
      for (int ks = 0; ks < 4; ++ks)
        acc[2 + mb][1] = mfma32(afr23[mb][ks], bfr1[ks], acc[2 + mb][1]);
    __builtin_amdgcn_s_setprio(0);
    TILE_END();
  }

  // Drain wrapped tail stages before LDS goes away / epilogue.
  asm volatile("s_waitcnt vmcnt(0)" ::: "memory");

  // epilogue: out = acc * (clampv/127) * qs[n] + bias[n]
  // C/D map: col = l31, row = (reg&3) + 8*(reg>>2) + 4*hi2.
  const float alpha = key_to_float(*keyp) * (1.0f / 127.0f);
  #pragma unroll
  for (int nb = 0; nb < 2; ++nb) {
    int n = bcol + wc * 64 + nb * 32 + l31;
    float sc = qs[n] * alpha;
    float bv = bias[n];
    #pragma unroll
    for (int mb = 0; mb < 4; ++mb) {
      int m0 = brow + wr * 128 + mb * 32 + 4 * hi2;
      #pragma unroll
      for (int reg = 0; reg < 16; ++reg) {
        int row = m0 + (reg & 3) + 8 * (reg >> 2);
        out[(size_t)row * NDIM + n] = (float)acc[mb][nb][reg] * sc + bv;
      }
    }
  }
}

extern "C" void kernel_launch(void* const* d_in, const int* in_sizes, int n_in,
                              void* d_out, int out_size, void* d_ws, size_t ws_size,
                              hipStream_t stream) {
  const float* x = (const float*)d_in[0];
  const int* wq = (const int*)d_in[1];       // integer input: int32 words
  const float* qscales = (const float*)d_in[2];
  const float* bias = (const float*)d_in[3];
  float* out = (float*)d_out;

  unsigned* keyp = (unsigned*)d_ws;
  signed char* x8 = (signed char*)d_ws + 256;
  signed char* w8 = x8 + (size_t)MDIM * KDIM;

  (void)hipMemsetAsync(keyp, 0, 4, stream);  // capture-safe
  kpackw<<<2048, 256, 0, stream>>>(wq, w8);
  kmax<<<2048, 256, 0, stream>>>(x, keyp);
  kquant<<<2048, 256, 0, stream>>>(x, x8, keyp);
  kgemm<<<(MDIM / BM) * (NDIM / BN), 512, 0, stream>>>(x8, w8, qscales, bias, keyp, out);
}